// Round 10
// baseline (169.386 us; speedup 1.0000x reference)
//
#include <hip/hip_runtime.h>

// PolylineEncoder: h = relu(X@W1+b1); feat = h@W2+b2; masked max over N=64 points.
// B=32 P=512 N=64 C=9 H=128.  R10: persistent-ish pipeline.
// Grid 2048, each block processes 4 tiles (tile = 2 polylines, strided by 2048).
// Per tile: X+mask prefetched into REGS during previous tile's GEMMs (HBM latency
// off the critical path), Xs double-buffered in LDS, only TWO barriers per tile
// (bA arena-reuse, bB Hb-ready) -- pool reduce via R2-verified shfl_xor butterfly,
// li==0 lanes store f32x4 directly.  Layer1/2 = verified 16x16x32 bf16 MFMA,
// frag-swizzled weights from prep1 (L1-hot after iter 0), XOR-swizzled Hb.

using bf16x8 = __attribute__((ext_vector_type(8))) short;
using f32x4  = __attribute__((ext_vector_type(4))) float;

#define MFMA32(A,B,C) __builtin_amdgcn_mfma_f32_16x16x32_bf16((A),(B),(C),0,0,0)

__device__ __forceinline__ f32x4 vmax4(f32x4 a, f32x4 b) {
  return __builtin_elementwise_max(a, b);
}

__device__ __forceinline__ unsigned short f2bf(float f) {
  union { float f; unsigned int u; } v; v.f = f;
  unsigned int r = v.u + 0x7fffu + ((v.u >> 16) & 1u);  // RNE
  return (unsigned short)(r >> 16);
}

// pack two floats to bf16x2 (round-half-up) via v_perm
__device__ __forceinline__ unsigned int pack_bf2(float a, float b) {
  union { float f; unsigned int u; } ua, ub; ua.f = a; ub.f = b;
  return __builtin_amdgcn_perm(ub.u + 0x8000u, ua.u + 0x8000u, 0x07060302u);
}

// ---------------- prep1: mask sniff + frag-swizzled weights ----------------
// ws: w1sw @0 (8KB) | w2sw @8192 (32KB) | flag @40960
__global__ void prep1(const float* __restrict__ W1, const float* __restrict__ W2,
                      const void* __restrict__ mask,
                      unsigned short* __restrict__ w1sw, unsigned short* __restrict__ w2sw,
                      int* __restrict__ flag) {
  int b = blockIdx.x, t = threadIdx.x;
  if (b == 0) {                      // mask storage sniff over 4096 bytes
    __shared__ int cnt;
    if (t == 0) cnt = 0;
    __syncthreads();
    const unsigned char* mb = (const unsigned char*)mask;
    int local = 0;
    for (int i = t * 16; i < t * 16 + 16; i++) local += (mb[i] != 0) ? 1 : 0;
    atomicAdd(&cnt, local);
    __syncthreads();
    if (t == 0) *flag = (cnt > 2800) ? 1 : 0;   // 1 = byte-wise mask, else int32-wise
  } else if (b <= 2) {
    // w1 A-frags (16x16x32): entry e = (wr*4+th)*64 + lane; h=(e>>6)*16+(lane&15)
    int e = (b - 1) * 256 + t;       // 512 entries x 8 halves = 8KB
    int lane = e & 63, grp = e >> 6;
    int li = lane & 15, q = lane >> 4;
    int h = grp * 16 + li;
    int c0 = q * 8;
    #pragma unroll
    for (int j = 0; j < 8; j++) {
      int c = c0 + j;
      w1sw[e * 8 + j] = f2bf((c < 9) ? W1[c * 128 + h] : 0.f);
    }
  } else {
    // w2 A-frags (16x16x32): entry e = (wr*16+ks*4+td)*64 + lane; 8 halves each
    int e = (b - 3) * 256 + t;       // 2048 entries x 8 halves = 32KB
    if (e < 2048) {
      int lane = e & 63, grp = e >> 6;
      int wr = grp >> 4, sub = grp & 15;
      int ks = sub >> 2, td = sub & 3;
      int li = lane & 15, q = lane >> 4;
      int d = wr * 64 + td * 16 + li;
      int h0 = ks * 32 + q * 8;
      #pragma unroll
      for (int j = 0; j < 8; j++)
        w2sw[e * 8 + j] = f2bf(W2[(h0 + j) * 128 + d]);
    }
  }
}

// ---------------- main ----------------
// LDS: Xs[2][1152] f32 (9216 B, ping-pong) + Hb 32768 B (XOR-swizzled H^T).
__global__ __launch_bounds__(256, 4) void poly_main_k(
    const float* __restrict__ X, const void* __restrict__ mask,
    const float* __restrict__ b1g, const float* __restrict__ b2g,
    const unsigned short* __restrict__ w1sw, const unsigned short* __restrict__ w2sw,
    const int* __restrict__ flagp, float* __restrict__ out)
{
  __shared__ __align__(16) float Xs[2][1152];
  __shared__ __align__(16) unsigned short Hb[128 * 128];

  const int tid  = threadIdx.x;
  const int lane = tid & 63;
  const int w    = tid >> 6;
  const int wr   = w >> 1, wc = w & 1;   // wr = h/d half, wc = polyline in tile
  const int li   = lane & 15, q = lane >> 4;
  const int flag = *flagp;

  const unsigned char* mp8  = (const unsigned char*)mask;
  const int*           mp32 = (const int*)mask;

  // ---- prologue: prefetch tile 0 (X + mask) into regs, stage Xs[0] ----
  long long tile = blockIdx.x;
  f32x4 xa, xb;
  unsigned int mcur[4];
  {
    const f32x4* xg = (const f32x4*)(X + tile * 1152);
    xa = xg[tid];
    int i2 = tid + 256; if (i2 > 287) i2 = 287;
    xb = xg[i2];
    long long mb = tile * 128 + wc * 64 + li;
    if (flag) {
      #pragma unroll
      for (int tm = 0; tm < 4; tm++) mcur[tm] = mp8[mb + tm * 16];
    } else {
      #pragma unroll
      for (int tm = 0; tm < 4; tm++) mcur[tm] = (unsigned int)mp32[mb + tm * 16];
    }
  }
  {
    f32x4* xl = (f32x4*)Xs[0];
    xl[tid] = xa;
    if (tid < 32) xl[tid + 256] = xb;
  }

  #pragma unroll
  for (int it = 0; it < 4; it++) {
    const int cur = it & 1;
    __syncthreads();  // bA: Xs[cur] visible; all prev-tile Hb reads done

    // ---- mask for current tile ----
    float mf[4];
    #pragma unroll
    for (int tm = 0; tm < 4; tm++) mf[tm] = mcur[tm] ? 0.f : -4e9f;

    // ---- layer-1 B-frags from Xs[cur]: B[m][k], k=q*8+j, only c<9 nonzero ----
    bf16x8 bx[4];
    #pragma unroll
    for (int tm = 0; tm < 4; tm++) {
      int m = wc * 64 + tm * 16 + li;
      const float* xr = Xs[cur] + m * 9;
      union { bf16x8 v; unsigned int u[4]; } uu;
      uu.u[0] = uu.u[1] = uu.u[2] = uu.u[3] = 0u;
      if (q == 0) {
        uu.u[0] = pack_bf2(xr[0], xr[1]); uu.u[1] = pack_bf2(xr[2], xr[3]);
        uu.u[2] = pack_bf2(xr[4], xr[5]); uu.u[3] = pack_bf2(xr[6], xr[7]);
      } else if (q == 1) {
        uu.u[0] = pack_bf2(xr[8], 0.f);
      }
      bx[tm] = uu.v;
    }

    // ---- prefetch NEXT tile (X + mask) into regs; consumed at iter end ----
    long long ntile = (long long)blockIdx.x + (long long)((it < 3) ? (it + 1) : it) * 2048;
    f32x4 xa2, xb2;
    unsigned int mnext[4];
    {
      const f32x4* xg2 = (const f32x4*)(X + ntile * 1152);
      xa2 = xg2[tid];
      int i2 = tid + 256; if (i2 > 287) i2 = 287;
      xb2 = xg2[i2];
      long long mb2 = ntile * 128 + wc * 64 + li;
      if (flag) {
        #pragma unroll
        for (int tm = 0; tm < 4; tm++) mnext[tm] = mp8[mb2 + tm * 16];
      } else {
        #pragma unroll
        for (int tm = 0; tm < 4; tm++) mnext[tm] = (unsigned int)mp32[mb2 + tm * 16];
      }
    }

    // ---- layer 1, th-outer, bias in MFMA C-init; swizzled Hb write ----
    #pragma unroll
    for (int th = 0; th < 4; th++) {
      bf16x8 a1 = *(const bf16x8*)(w1sw + ((wr * 4 + th) * 64 + lane) * 8);
      f32x4 bv = *(const f32x4*)(b1g + wr * 64 + th * 16 + q * 4);
      f32x4 acc[4];
      #pragma unroll
      for (int tm = 0; tm < 4; tm++) acc[tm] = bv;
      #pragma unroll
      for (int tm = 0; tm < 4; tm++) acc[tm] = MFMA32(a1, bx[tm], acc[tm]);
      #pragma unroll
      for (int tm = 0; tm < 4; tm++) {
        int m = wc * 64 + tm * 16 + li;
        f32x4 v = vmax4(acc[tm], f32x4{0.f, 0.f, 0.f, 0.f});
        uint2 hv;
        hv.x = pack_bf2(v[0], v[1]);
        hv.y = pack_bf2(v[2], v[3]);
        int chunk = (wr * 8 + th * 2 + (q >> 1)) ^ li;   // 16B-chunk XOR swizzle
        *(uint2*)(Hb + m * 128 + chunk * 8 + (q & 1) * 4) = hv;
      }
    }
    __syncthreads();  // bB: Hb ready

    // ---- layer 2, tm-outer with incremental pool; weights via L1-hot loads ----
    f32x4 pooled[4];
    #pragma unroll
    for (int tm = 0; tm < 4; tm++) {
      int m = wc * 64 + tm * 16 + li;
      f32x4 acc[4];
      #pragma unroll
      for (int td = 0; td < 4; td++) acc[td] = f32x4{0.f, 0.f, 0.f, 0.f};
      #pragma unroll
      for (int ks = 0; ks < 4; ks++) {
        int chunk = (ks * 4 + q) ^ li;                  // read swizzle, 16B aligned
        bf16x8 bb = *(const bf16x8*)(Hb + m * 128 + chunk * 8);
        #pragma unroll
        for (int td = 0; td < 4; td++) {
          bf16x8 a2 = *(const bf16x8*)(w2sw + (((wr * 16 + ks * 4 + td) * 64) + lane) * 8);
          acc[td] = MFMA32(a2, bb, acc[td]);
        }
      }
      if (tm == 0) {
        #pragma unroll
        for (int td = 0; td < 4; td++) pooled[td] = acc[td] + mf[0];
      } else {
        #pragma unroll
        for (int td = 0; td < 4; td++) pooled[td] = vmax4(pooled[td], acc[td] + mf[tm]);
      }
    }
    #pragma unroll
    for (int td = 0; td < 4; td++)
      pooled[td] += *(const f32x4*)(b2g + wr * 64 + td * 16 + q * 4);

    // ---- reduce over 16 li-lanes with shfl_xor (R2-verified), li==0 stores ----
    #pragma unroll
    for (int s = 8; s >= 1; s >>= 1) {
      #pragma unroll
      for (int td = 0; td < 4; td++) {
        #pragma unroll
        for (int r = 0; r < 4; r++) {
          float o = __shfl_xor(pooled[td][r], s, 64);
          pooled[td][r] = fmaxf(pooled[td][r], o);
        }
      }
    }
    if (li == 0) {
      long long poly = tile * 2 + wc;
      #pragma unroll
      for (int td = 0; td < 4; td++) {
        f32x4 v = pooled[td];
        #pragma unroll
        for (int r = 0; r < 4; r++) if (v[r] < -1e8f) v[r] = 0.f;
        *(f32x4*)(out + poly * 128 + wr * 64 + td * 16 + q * 4) = v;
      }
    }

    // ---- stage next X into the other Xs buffer (visible after next bA) ----
    {
      f32x4* xl = (f32x4*)Xs[cur ^ 1];
      xl[tid] = xa2;
      if (tid < 32) xl[tid + 256] = xb2;
    }
    #pragma unroll
    for (int tm = 0; tm < 4; tm++) mcur[tm] = mnext[tm];
    tile = ntile;
  }
}

extern "C" void kernel_launch(void* const* d_in, const int* in_sizes, int n_in,
                              void* d_out, int out_size, void* d_ws, size_t ws_size,
                              hipStream_t stream) {
  const float* X    = (const float*)d_in[0];
  const void*  mask = d_in[1];
  const float* W1   = (const float*)d_in[2];
  const float* b1   = (const float*)d_in[3];
  const float* W2   = (const float*)d_in[4];
  const float* b2   = (const float*)d_in[5];
  float* out = (float*)d_out;

  unsigned short* w1sw = (unsigned short*)d_ws;
  unsigned short* w2sw = (unsigned short*)((char*)d_ws + 8192);
  int* flag            = (int*)((char*)d_ws + 40960);

  prep1<<<11, 256, 0, stream>>>(W1, W2, mask, w1sw, w2sw, flag);
  poly_main_k<<<2048, 256, 0, stream>>>(X, mask, b1, b2, w1sw, w2sw, flag, out);
}

// Round 11
// 155.695 us; speedup vs baseline: 1.0879x; 1.0879x over previous
//
#include <hip/hip_runtime.h>

// PolylineEncoder: h = relu(X@W1+b1); feat = h@W2+b2; masked max over N=64 points.
// B=32 P=512 N=64 C=9 H=128.  Block = 2 polylines (128 points), grid 8192.
// R11 = R7 with the barrier count cut 5 -> 2:
//  - Xs gets its own 4.6KB LDS region (no Xs/Hb union)   -> drops bfb
//  - pool epilogue = shfl_xor butterfly + li==0 f32x4 stores (R10 proved this
//    is full-line write traffic: WRITE_SIZE exactly 8MB)  -> drops b2 + b3
// Everything else identical to R7 (best known: 70us main): verified 16x16x32
// MFMA both layers, frag-swizzled weights, XOR-swizzled Hb, bias in C-init,
// direct mask loads, launch_bounds(256,4) (bounds=5 spills: R5/R6/R9).
// LDS 37376 B -> 4 blocks/CU.

using bf16x8 = __attribute__((ext_vector_type(8))) short;
using f32x4  = __attribute__((ext_vector_type(4))) float;

#define MFMA32(A,B,C) __builtin_amdgcn_mfma_f32_16x16x32_bf16((A),(B),(C),0,0,0)

__device__ __forceinline__ f32x4 vmax4(f32x4 a, f32x4 b) {
  return __builtin_elementwise_max(a, b);
}

__device__ __forceinline__ unsigned short f2bf(float f) {
  union { float f; unsigned int u; } v; v.f = f;
  unsigned int r = v.u + 0x7fffu + ((v.u >> 16) & 1u);  // RNE
  return (unsigned short)(r >> 16);
}

// pack two floats to bf16x2 (round-half-up) via v_perm
__device__ __forceinline__ unsigned int pack_bf2(float a, float b) {
  union { float f; unsigned int u; } ua, ub; ua.f = a; ub.f = b;
  return __builtin_amdgcn_perm(ub.u + 0x8000u, ua.u + 0x8000u, 0x07060302u);
}

// ---------------- prep1: mask sniff + frag-swizzled weights ----------------
// ws: w1sw @0 (8KB) | w2sw @8192 (32KB) | flag @40960
__global__ void prep1(const float* __restrict__ W1, const float* __restrict__ W2,
                      const void* __restrict__ mask,
                      unsigned short* __restrict__ w1sw, unsigned short* __restrict__ w2sw,
                      int* __restrict__ flag) {
  int b = blockIdx.x, t = threadIdx.x;
  if (b == 0) {                      // mask storage sniff over 4096 bytes
    __shared__ int cnt;
    if (t == 0) cnt = 0;
    __syncthreads();
    const unsigned char* mb = (const unsigned char*)mask;
    int local = 0;
    for (int i = t * 16; i < t * 16 + 16; i++) local += (mb[i] != 0) ? 1 : 0;
    atomicAdd(&cnt, local);
    __syncthreads();
    if (t == 0) *flag = (cnt > 2800) ? 1 : 0;   // 1 = byte-wise mask, else int32-wise
  } else if (b <= 2) {
    // w1 A-frags (16x16x32): entry e = (wr*4+th)*64 + lane; h=(e>>6)*16+(lane&15)
    int e = (b - 1) * 256 + t;       // 512 entries x 8 halves = 8KB
    int lane = e & 63, grp = e >> 6;
    int li = lane & 15, q = lane >> 4;
    int h = grp * 16 + li;
    int c0 = q * 8;
    #pragma unroll
    for (int j = 0; j < 8; j++) {
      int c = c0 + j;
      w1sw[e * 8 + j] = f2bf((c < 9) ? W1[c * 128 + h] : 0.f);
    }
  } else {
    // w2 A-frags (16x16x32): entry e = (wr*16+ks*4+td)*64 + lane; 8 halves each
    int e = (b - 3) * 256 + t;       // 2048 entries x 8 halves = 32KB
    if (e < 2048) {
      int lane = e & 63, grp = e >> 6;
      int wr = grp >> 4, sub = grp & 15;
      int ks = sub >> 2, td = sub & 3;
      int li = lane & 15, q = lane >> 4;
      int d = wr * 64 + td * 16 + li;
      int h0 = ks * 32 + q * 8;
      #pragma unroll
      for (int j = 0; j < 8; j++)
        w2sw[e * 8 + j] = f2bf(W2[(h0 + j) * 128 + d]);
    }
  }
}

// ---------------- main ----------------
// LDS: Xs 4608 B (own region) + Hb 32768 B (XOR-swizzled H^T).  2 barriers.
__global__ __launch_bounds__(256, 4) void poly_main_k(
    const float* __restrict__ X, const void* __restrict__ mask,
    const float* __restrict__ b1g, const float* __restrict__ b2g,
    const unsigned short* __restrict__ w1sw, const unsigned short* __restrict__ w2sw,
    const int* __restrict__ flagp, float* __restrict__ out)
{
  __shared__ __align__(16) float Xs[1152];
  __shared__ __align__(16) unsigned short Hb[128 * 128];

  const int tid  = threadIdx.x;
  const int lane = tid & 63;
  const int w    = tid >> 6;
  const int wr   = w >> 1, wc = w & 1;   // wr = h/d half, wc = polyline in block
  const int li   = lane & 15, q = lane >> 4;

  // ---- mask: direct loads; all 4 per lane sit in one 64B line (byte case) ----
  float mf[4];
  {
    int flag = *flagp;
    long long mb = (long long)blockIdx.x * 128 + wc * 64 + li;
    if (flag) {
      const unsigned char* mp = (const unsigned char*)mask;
      #pragma unroll
      for (int tm = 0; tm < 4; tm++) mf[tm] = mp[mb + tm * 16] ? 0.f : -4e9f;
    } else {
      const int* mp = (const int*)mask;
      #pragma unroll
      for (int tm = 0; tm < 4; tm++) mf[tm] = mp[mb + tm * 16] ? 0.f : -4e9f;
    }
  }

  // ---- stage X: 288 float4 coalesced global -> LDS b128 ----
  {
    const f32x4* xg = (const f32x4*)(X + (long long)blockIdx.x * 1152);
    f32x4* xl = (f32x4*)Xs;
    xl[tid] = xg[tid];
    if (tid < 32) xl[tid + 256] = xg[tid + 256];
  }
  __syncthreads();  // b0: Xs ready

  // ---- layer-1 B-frags from Xs: B[m][k], k=q*8+j, only c<9 nonzero ----
  bf16x8 bx[4];
  #pragma unroll
  for (int tm = 0; tm < 4; tm++) {
    int m = wc * 64 + tm * 16 + li;
    const float* xr = Xs + m * 9;
    union { bf16x8 v; unsigned int u[4]; } uu;
    uu.u[0] = uu.u[1] = uu.u[2] = uu.u[3] = 0u;
    if (q == 0) {
      uu.u[0] = pack_bf2(xr[0], xr[1]); uu.u[1] = pack_bf2(xr[2], xr[3]);
      uu.u[2] = pack_bf2(xr[4], xr[5]); uu.u[3] = pack_bf2(xr[6], xr[7]);
    } else if (q == 1) {
      uu.u[0] = pack_bf2(xr[8], 0.f);
    }
    bx[tm] = uu.v;
  }

  // ---- layer 1, th-outer: bias folded into MFMA C-init ----
  #pragma unroll
  for (int th = 0; th < 4; th++) {
    bf16x8 a1 = *(const bf16x8*)(w1sw + ((wr * 4 + th) * 64 + lane) * 8);
    f32x4 bv = *(const f32x4*)(b1g + wr * 64 + th * 16 + q * 4);
    f32x4 acc[4];
    #pragma unroll
    for (int tm = 0; tm < 4; tm++) acc[tm] = bv;
    #pragma unroll
    for (int tm = 0; tm < 4; tm++) acc[tm] = MFMA32(a1, bx[tm], acc[tm]);
    // epilogue: relu (packed max), pack, swizzled H^T write
    // write chunk (16B units): (wr*8 + th*2 + (q>>1)) ^ li, inner (q&1)*8B
    #pragma unroll
    for (int tm = 0; tm < 4; tm++) {
      int m = wc * 64 + tm * 16 + li;
      f32x4 v = vmax4(acc[tm], f32x4{0.f, 0.f, 0.f, 0.f});
      uint2 hv;
      hv.x = pack_bf2(v[0], v[1]);
      hv.y = pack_bf2(v[2], v[3]);
      int chunk = (wr * 8 + th * 2 + (q >> 1)) ^ li;
      *(uint2*)(Hb + m * 128 + chunk * 8 + (q & 1) * 4) = hv;
    }
  }
  __syncthreads();  // b1: Hb ready (the last barrier)

  // ---- layer 2, tm-outer with incremental pool; a2 loads L1-hot ----
  f32x4 pooled[4];
  #pragma unroll
  for (int tm = 0; tm < 4; tm++) {
    int m = wc * 64 + tm * 16 + li;
    f32x4 acc[4];
    #pragma unroll
    for (int td = 0; td < 4; td++) acc[td] = f32x4{0.f, 0.f, 0.f, 0.f};
    #pragma unroll
    for (int ks = 0; ks < 4; ks++) {
      int chunk = (ks * 4 + q) ^ li;             // read swizzle, 16B aligned
      bf16x8 bb = *(const bf16x8*)(Hb + m * 128 + chunk * 8);
      #pragma unroll
      for (int td = 0; td < 4; td++) {
        bf16x8 a2 = *(const bf16x8*)(w2sw + (((wr * 16 + ks * 4 + td) * 64) + lane) * 8);
        acc[td] = MFMA32(a2, bb, acc[td]);
      }
    }
    if (tm == 0) {
      #pragma unroll
      for (int td = 0; td < 4; td++) pooled[td] = acc[td] + mf[0];
    } else {
      #pragma unroll
      for (int td = 0; td < 4; td++) pooled[td] = vmax4(pooled[td], acc[td] + mf[tm]);
    }
  }
  // bias after max (uniform over m)
  #pragma unroll
  for (int td = 0; td < 4; td++)
    pooled[td] += *(const f32x4*)(b2g + wr * 64 + td * 16 + q * 4);

  // ---- reduce over 16 li-lanes with shfl_xor (R2/R10-verified) ----
  #pragma unroll
  for (int s = 8; s >= 1; s >>= 1) {
    #pragma unroll
    for (int td = 0; td < 4; td++) {
      #pragma unroll
      for (int r = 0; r < 4; r++) {
        float o = __shfl_xor(pooled[td][r], s, 64);
        pooled[td][r] = fmaxf(pooled[td][r], o);
      }
    }
  }

  // ---- li==0 lanes store f32x4 (full-line traffic: R10 WRITE_SIZE=8MB) ----
  if (li == 0) {
    long long poly = (long long)blockIdx.x * 2 + wc;
    #pragma unroll
    for (int td = 0; td < 4; td++) {
      f32x4 v = pooled[td];
      #pragma unroll
      for (int r = 0; r < 4; r++) if (v[r] < -1e8f) v[r] = 0.f;
      *(f32x4*)(out + poly * 128 + wr * 64 + td * 16 + q * 4) = v;
    }
  }
}

extern "C" void kernel_launch(void* const* d_in, const int* in_sizes, int n_in,
                              void* d_out, int out_size, void* d_ws, size_t ws_size,
                              hipStream_t stream) {
  const float* X    = (const float*)d_in[0];
  const void*  mask = d_in[1];
  const float* W1   = (const float*)d_in[2];
  const float* b1   = (const float*)d_in[3];
  const float* W2   = (const float*)d_in[4];
  const float* b2   = (const float*)d_in[5];
  float* out = (float*)d_out;

  unsigned short* w1sw = (unsigned short*)d_ws;
  unsigned short* w2sw = (unsigned short*)((char*)d_ws + 8192);
  int* flag            = (int*)((char*)d_ws + 40960);

  prep1<<<11, 256, 0, stream>>>(W1, W2, mask, w1sw, w2sw, flag);
  poly_main_k<<<8192, 256, 0, stream>>>(X, mask, b1, b2, w1sw, w2sw, flag, out);
}